// Round 22
// baseline (240.882 us; speedup 1.0000x reference)
//
#include <hip/hip_runtime.h>
#include <cstdint>

#define BB 16
#define MM 128
#define TT 12000
constexpr int BT = BB * TT; // 192000

// Q4-interleaved scan layout: element (row b, pos t), t=4g+j lives at
// q[(g*16 + b)*4 + j]. Group = 256 B (16 rows x 16 B). SB = 4 groups.
// Chunk = 12 SBs = 48 groups = 12288 B. 64 chunks = 768 SBs (750 real).

// K1: per-column stats over the M axis, sequential in m (reference order).
// anti-fma via `#pragma clang fp contract(off)` (proven round 13).
__global__ void k1_colstats(const float* __restrict__ mel,
                            float* __restrict__ ssq,
                            float* __restrict__ dotv,
                            float* __restrict__ cmean,
                            unsigned int* __restrict__ counts) {
    if (blockIdx.x == 0 && blockIdx.y == 0 && threadIdx.x < 8)
        counts[threadIdx.x] = 0u;
    const int b = blockIdx.y;
    const int t = blockIdx.x * blockDim.x + threadIdx.x;
    if (t >= TT) return;
    const float* base = mel + (size_t)b * MM * TT;
    float accd = 0.f, accq = 0.f, accs = 0.f;
    {
#pragma clang fp contract(off)
        for (int m = 0; m < MM; ++m) {
            const float* rowp = base + (size_t)m * TT;
            float cur = rowp[t];
            float prev = (t > 0) ? rowp[t - 1] : 0.f;
            accd += prev * cur;
            accq += cur * cur;
            accs += cur;
        }
    }
    size_t i = (size_t)b * TT + t;
    ssq[i] = accq; dotv[i] = accd; cmean[i] = accs * (1.0f / MM);
}

// kA: temporal = 1 - std(smooth, ddof=1). Row staged to LDS once.
__global__ void kA_temporal(const float* __restrict__ cmean,
                            float* __restrict__ temporal) {
    const int b = blockIdx.x;
    const int tid = threadIdx.x;
    __shared__ __align__(16) float row_s[TT];
    __shared__ float red[256];
    __shared__ float mean_s;
    const float4* c4 = (const float4*)(cmean + (size_t)b * TT);
    float4* r4 = (float4*)row_s;
    for (int i = tid; i < TT / 4; i += 256) r4[i] = c4[i];
    __syncthreads();

    float s = 0.f;
    for (int t = tid; t < TT; t += 256) {
        float v = 0.f;
        int lo = t - 2 < 0 ? 0 : t - 2;
        int hi = t + 2 >= TT ? TT - 1 : t + 2;
        for (int j = lo; j <= hi; ++j) v += row_s[j];
        s += v / 5.0f;
    }
    red[tid] = s; __syncthreads();
    for (int o = 128; o > 0; o >>= 1) {
        if (tid < o) red[tid] += red[tid + o];
        __syncthreads();
    }
    if (tid == 0) mean_s = red[0] / (float)TT;
    __syncthreads();
    float mean = mean_s;
    float ss = 0.f;
    for (int t = tid; t < TT; t += 256) {
        float v = 0.f;
        int lo = t - 2 < 0 ? 0 : t - 2;
        int hi = t + 2 >= TT ? TT - 1 : t + 2;
        for (int j = lo; j <= hi; ++j) v += row_s[j];
        float sm = v / 5.0f - mean;
        ss += sm * sm;
    }
    red[tid] = ss; __syncthreads();
    for (int o = 128; o > 0; o >>= 1) {
        if (tid < o) red[tid] += red[tid + o];
        __syncthreads();
    }
    if (tid == 0) {
        float var = red[0] / (float)(TT - 1);
        temporal[b] = 1.0f - sqrtf(var);
    }
}

// kB: cons — same arithmetic as the passing version; also writes the
// Q4-interleaved copy for the scan (same value, extra store only).
__global__ void kB_cons(const float* __restrict__ ssq,
                        const float* __restrict__ dotv,
                        const float* __restrict__ spec,
                        const float* __restrict__ temporal,
                        const float* __restrict__ wraw,
                        float* __restrict__ cons,
                        float* __restrict__ consq) {
    const int idx = blockIdx.x * 256 + threadIdx.x;
    const int b = idx / TT;
    const int t = idx - b * TT;
    float x0 = wraw[0], x1 = wraw[1], x2 = wraw[2];
    float mx = fmaxf(x0, fmaxf(x1, x2));
    float e0 = expf(x0 - mx), e1 = expf(x1 - mx), e2 = expf(x2 - mx);
    float es = (e0 + e1) + e2;
    float w0 = e0 / es, w1 = e1 / es, w2 = e2 / es;
    float mel_sim, spec_sim;
    if (t == 0) { mel_sim = 0.f; spec_sim = 1.f; }
    else {
        float na = fmaxf(sqrtf(ssq[idx - 1]), 1e-8f);
        float nb = fmaxf(sqrtf(ssq[idx]),     1e-8f);
        float den = na * nb; asm volatile("" : "+v"(den));
        mel_sim = dotv[idx] / den;
        float d = fabsf(spec[idx] - spec[idx - 1]);
        spec_sim = 1.0f / (1.0f + d);
    }
    float pa = w0 * mel_sim;     asm volatile("" : "+v"(pa));
    float pb = w1 * spec_sim;    asm volatile("" : "+v"(pb));
    float pc = w2 * temporal[b]; asm volatile("" : "+v"(pc));
    float c = (pa + pb) + pc;
    cons[idx] = c;
    consq[((t >> 2) * 16 + b) * 4 + (t & 3)] = c;
}

// One SB (4 groups, 16 lanes lockstep): wait vmcnt(44) (48-load pure ring),
// 16 chained adds (bitwise reference order), carry snapshot, 4 ds_writes
// (CS -> LDS out buffer, lgkm — not in wave0's vmcnt), 4 prefetch loads
// 12 SBs ahead, self-advancing addresses (+1024 each).
#define SBX(a0,a1,a2,a3, b0,b1,b2,b3, c0,c1,c2,c3, d0,d1,d2,d3) \
    "s_waitcnt vmcnt(44)\n\t" \
    "v_add_f32 v" a0 ", v43, v" a0 "\n\t" \
    "v_add_f32 v" a1 ", v" a0 ", v" a1 "\n\t" \
    "v_add_f32 v" a2 ", v" a1 ", v" a2 "\n\t" \
    "v_add_f32 v" a3 ", v" a2 ", v" a3 "\n\t" \
    "v_add_f32 v" b0 ", v" a3 ", v" b0 "\n\t" \
    "v_add_f32 v" b1 ", v" b0 ", v" b1 "\n\t" \
    "v_add_f32 v" b2 ", v" b1 ", v" b2 "\n\t" \
    "v_add_f32 v" b3 ", v" b2 ", v" b3 "\n\t" \
    "v_add_f32 v" c0 ", v" b3 ", v" c0 "\n\t" \
    "v_add_f32 v" c1 ", v" c0 ", v" c1 "\n\t" \
    "v_add_f32 v" c2 ", v" c1 ", v" c2 "\n\t" \
    "v_add_f32 v" c3 ", v" c2 ", v" c3 "\n\t" \
    "v_add_f32 v" d0 ", v" c3 ", v" d0 "\n\t" \
    "v_add_f32 v" d1 ", v" d0 ", v" d1 "\n\t" \
    "v_add_f32 v" d2 ", v" d1 ", v" d2 "\n\t" \
    "v_add_f32 v" d3 ", v" d2 ", v" d3 "\n\t" \
    "v_mov_b32 v43, v" d3 "\n\t" \
    "ds_write_b128 v44, v[" a0 ":" a3 "] offset:0\n\t" \
    "ds_write_b128 v44, v[" b0 ":" b3 "] offset:256\n\t" \
    "ds_write_b128 v44, v[" c0 ":" c3 "] offset:512\n\t" \
    "ds_write_b128 v44, v[" d0 ":" d3 "] offset:768\n\t" \
    "global_load_dwordx4 v[" a0 ":" a3 "], v40, %0 offset:0\n\t" \
    "global_load_dwordx4 v[" b0 ":" b3 "], v40, %0 offset:256\n\t" \
    "global_load_dwordx4 v[" c0 ":" c3 "], v40, %0 offset:512\n\t" \
    "global_load_dwordx4 v[" d0 ":" d3 "], v40, %0 offset:768\n\t" \
    "v_add_u32 v44, 0x400, v44\n\t" \
    "v_add_u32 v40, 0x400, v40\n\t"

// Prologue SB: issue 4 loads, advance load pointer.
#define PRO(a0,a1,a2,a3, b0,b1,b2,b3, c0,c1,c2,c3, d0,d1,d2,d3) \
    "global_load_dwordx4 v[" a0 ":" a3 "], v40, %0 offset:0\n\t" \
    "global_load_dwordx4 v[" b0 ":" b3 "], v40, %0 offset:256\n\t" \
    "global_load_dwordx4 v[" c0 ":" c3 "], v40, %0 offset:512\n\t" \
    "global_load_dwordx4 v[" d0 ":" d3 "], v40, %0 offset:768\n\t" \
    "v_add_u32 v40, 0x400, v40\n\t"

// 12 ring SB register sets (quads), v48..v239.
#define R0  "48","49","50","51","52","53","54","55","56","57","58","59","60","61","62","63"
#define R1  "64","65","66","67","68","69","70","71","72","73","74","75","76","77","78","79"
#define R2  "80","81","82","83","84","85","86","87","88","89","90","91","92","93","94","95"
#define R3  "96","97","98","99","100","101","102","103","104","105","106","107","108","109","110","111"
#define R4  "112","113","114","115","116","117","118","119","120","121","122","123","124","125","126","127"
#define R5  "128","129","130","131","132","133","134","135","136","137","138","139","140","141","142","143"
#define R6  "144","145","146","147","148","149","150","151","152","153","154","155","156","157","158","159"
#define R7  "160","161","162","163","164","165","166","167","168","169","170","171","172","173","174","175"
#define R8  "176","177","178","179","180","181","182","183","184","185","186","187","188","189","190","191"
#define R9  "192","193","194","195","196","197","198","199","200","201","202","203","204","205","206","207"
#define R10 "208","209","210","211","212","213","214","215","216","217","218","219","220","221","222","223"
#define R11 "224","225","226","227","228","229","230","231","232","233","234","235","236","237","238","239"
#define XP(M, ...) M(__VA_ARGS__)

#define CHUNK12 \
    XP(SBX, R0)  XP(SBX, R1)  XP(SBX, R2)  XP(SBX, R3) \
    XP(SBX, R4)  XP(SBX, R5)  XP(SBX, R6)  XP(SBX, R7) \
    XP(SBX, R8)  XP(SBX, R9)  XP(SBX, R10) XP(SBX, R11) \
    "s_waitcnt lgkmcnt(0)\n\t" \
    "s_barrier\n\t"

// kC: 16-lane SIMT scan (wave 0), 48-group pure-load global ring; CS ->
// LDS double buffer; wave 1 = L1 WARMER (streams chunk c+2's consq into
// this CU's L1 so wave0's ring loads hit L1 instead of remote-L2/L3);
// waves 2-3 copy CS chunks LDS -> global. Raw s_barrier (64 per wave).
__global__ void __launch_bounds__(256)
kC_scan16(const float* __restrict__ consq,
          float* __restrict__ CSq) {
    const int tid = threadIdx.x;
    __shared__ __align__(16) float lbuf[6144];   // 2 x 12288 B

    if (tid < 64) {
        if (tid < BB) {
            uint32_t goff  = (uint32_t)(tid * 16);
            uint32_t laddr = (uint32_t)(uintptr_t)&lbuf[0] + (uint32_t)(tid * 16);
            asm volatile(
                "v_mov_b32 v40, %1\n\t"     // global load byte offset
                "v_mov_b32 v44, %2\n\t"     // LDS write addr
                "v_mov_b32 v43, 0\n\t"      // carry
                XP(PRO, R0)  XP(PRO, R1)  XP(PRO, R2)  XP(PRO, R3)
                XP(PRO, R4)  XP(PRO, R5)  XP(PRO, R6)  XP(PRO, R7)
                XP(PRO, R8)  XP(PRO, R9)  XP(PRO, R10) XP(PRO, R11)
                "s_mov_b32 s20, 32\n\t"     // 32 x 2 chunks = 64 chunks
                "3:\n\t"
                CHUNK12                      // chunk even -> lbuf[0..12287]
                CHUNK12                      // chunk odd  -> lbuf[12288..24575]
                "v_add_u32 v44, 0xffffa000, v44\n\t"   // rewind 24576
                "s_sub_u32 s20, s20, 1\n\t"
                "s_cmp_lg_u32 s20, 0\n\t"
                "s_cbranch_scc1 3b\n\t"
                "s_waitcnt vmcnt(0) lgkmcnt(0)\n\t"
                :
                : "s"(consq), "v"(goff), "v"(laddr)
                : "v40", "v43", "v44",
                  "v48","v49","v50","v51","v52","v53","v54","v55",
                  "v56","v57","v58","v59","v60","v61","v62","v63",
                  "v64","v65","v66","v67","v68","v69","v70","v71",
                  "v72","v73","v74","v75","v76","v77","v78","v79",
                  "v80","v81","v82","v83","v84","v85","v86","v87",
                  "v88","v89","v90","v91","v92","v93","v94","v95",
                  "v96","v97","v98","v99","v100","v101","v102","v103",
                  "v104","v105","v106","v107","v108","v109","v110","v111",
                  "v112","v113","v114","v115","v116","v117","v118","v119",
                  "v120","v121","v122","v123","v124","v125","v126","v127",
                  "v128","v129","v130","v131","v132","v133","v134","v135",
                  "v136","v137","v138","v139","v140","v141","v142","v143",
                  "v144","v145","v146","v147","v148","v149","v150","v151",
                  "v152","v153","v154","v155","v156","v157","v158","v159",
                  "v160","v161","v162","v163","v164","v165","v166","v167",
                  "v168","v169","v170","v171","v172","v173","v174","v175",
                  "v176","v177","v178","v179","v180","v181","v182","v183",
                  "v184","v185","v186","v187","v188","v189","v190","v191",
                  "v192","v193","v194","v195","v196","v197","v198","v199",
                  "v200","v201","v202","v203","v204","v205","v206","v207",
                  "v208","v209","v210","v211","v212","v213","v214","v215",
                  "v216","v217","v218","v219","v220","v221","v222","v223",
                  "v224","v225","v226","v227","v228","v229","v230","v231",
                  "v232","v233","v234","v235","v236","v237","v238","v239",
                  "s20", "scc", "memory");
        } else {
            // inactive lanes of wave 0 ride along via exec-masked asm above;
            // nothing to do here (the barriers live inside the asm block,
            // executed by wave 0 as a whole).
        }
    } else if (tid < 128) {
        // wave 1: L1 warmer — stream chunk c+2 of consq (12 KB) into L1.
        const float4* s4 = (const float4*)consq;
        const int lane = tid - 64;
        for (int c = 0; c < 64; ++c) {
            if (c + 2 < 64) {
                const float4* w4 = s4 + (size_t)(c + 2) * 768;
#pragma unroll
                for (int i = 0; i < 12; ++i) {
                    float4 v = w4[lane + 64 * i];
                    asm volatile("" :: "v"(v.x), "v"(v.y), "v"(v.z), "v"(v.w));
                }
            }
            asm volatile("s_barrier" ::: "memory");
        }
    } else {
        // waves 2-3: after barrier c, copy CS chunk c (12 KB) LDS -> global.
        float4* dst4 = (float4*)CSq;
        const float4* b4 = (const float4*)lbuf;
        const int lane = tid - 128;
        for (int c = 0; c < 64; ++c) {
            asm volatile("s_barrier" ::: "memory");
            const float4* s4 = b4 + (size_t)(c & 1) * 768;
            float4* d4 = dst4 + (size_t)c * 768;
            for (int i = lane; i < 768; i += 128) d4[i] = s4[i];
        }
    }
}

// kD: candbits + local/step + 5-iter never-done sim. CS read from the
// Q4-interleaved buffer (same values bitwise). Flags instead of counts.
__global__ void kD_prepare(const float* __restrict__ cons,
                           const float* __restrict__ CSq,
                           const float* __restrict__ init,
                           float* __restrict__ stepv,
                           float* __restrict__ candf,
                           unsigned int* __restrict__ counts) {
    const int idx = blockIdx.x * 256 + threadIdx.x;
    const int b = idx / TT;
    const int t = idx - b * TT;
    __shared__ unsigned sflag[5];
    if (threadIdx.x < 5) sflag[threadIdx.x] = 0u;
    __syncthreads();

    int lo = t - 2; if (lo < 0) lo = 0;
    int hi = t + 3; if (hi > TT) hi = TT;
    int uh = hi - 1;
    float csH = CSq[((uh >> 2) * 16 + b) * 4 + (uh & 3)];
    float csL = 0.f;
    if (lo > 0) {
        int ul = lo - 1;
        csL = CSq[((ul >> 2) * 16 + b) * 4 + (ul & 3)];
    }
    float local = (csH - csL) / (float)(hi - lo);
    float dir = (local > 0.7f) ? -0.1f : ((local < 0.4f) ? 0.1f : 0.0f);
    bool interior = (t >= 1) && (t <= TT - 2);
    float step = interior ? dir : 0.0f;
    float g = (t == 0) ? 0.f : fabsf(cons[idx] - cons[idx - 1]);
    float cand = (g > 0.15f) ? 1.f : 0.f;
    float r = init[idx];
    bool nz[5];
#pragma unroll
    for (int j = 0; j < 5; ++j) {
        float adj = (fmaxf(cand, r) > 0.5f) ? step : 0.0f;
        nz[j] = (adj != 0.0f);
        r = fminf(fmaxf(r + adj, 0.0f), 1.0f);
    }
    stepv[idx] = step; candf[idx] = cand;
    const int lane = threadIdx.x & 63;
#pragma unroll
    for (int j = 0; j < 5; ++j) {
        unsigned long long mb = __ballot(nz[j]);
        if (lane == 0 && mb) atomicOr(&sflag[j], 1u);   // LDS-scope, cheap
    }
    __syncthreads();
    if (threadIdx.x < 5 && sflag[threadIdx.x]) counts[threadIdx.x] = 1u;
}

// K_final: freeze at the first iteration whose adjustment flag is 0.
__global__ void k_final(const float* __restrict__ init,
                        const float* __restrict__ stepv,
                        const float* __restrict__ candf,
                        const unsigned int* __restrict__ counts,
                        float* __restrict__ outp) {
    const int idx = blockIdx.x * 256 + threadIdx.x;
    float r = init[idx];
    float step = stepv[idx];
    float cand = candf[idx];
    unsigned c[5];
#pragma unroll
    for (int j = 0; j < 5; ++j) c[j] = counts[j];
#pragma unroll
    for (int j = 0; j < 5; ++j) {
        if (c[j] == 0u) break;
        float adj = (fmaxf(cand, r) > 0.5f) ? step : 0.0f;
        r = fminf(fmaxf(r + adj, 0.0f), 1.0f);
    }
    outp[idx] = r;
}

extern "C" void kernel_launch(void* const* d_in, const int* in_sizes, int n_in,
                              void* d_out, int out_size, void* d_ws, size_t ws_size,
                              hipStream_t stream) {
    const float* mel  = (const float*)d_in[0];
    const float* spec = (const float*)d_in[1];
    const float* init = (const float*)d_in[2];
    const float* wts  = (const float*)d_in[3];

    float* ws = (float*)d_ws;
    float* ssq   = ws;                 // 192000
    float* dotv  = ws + 192000;        // 192000
    float* cmean = ws + 384000;        // 192000
    float* cons  = ws + 576000;        // 192000 (row-major, for kD)
    float* consq = ws + 768000;        // 199680 (Q4; ring-lookahead pad)
    float* CSq   = ws + 967680;        // 196608 (Q4; 768-SB store region)
    float* stepv = ws + 1164288;       // 192000
    float* candf = ws + 1356288;       // 192000
    float* temporal = ws + 1548288;    // 16
    unsigned int* counts = (unsigned int*)(ws + 1548304); // 8 u32

    dim3 g1((TT + 255) / 256, BB);
    k1_colstats<<<g1, 256, 0, stream>>>(mel, ssq, dotv, cmean, counts);
    kA_temporal<<<BB, 256, 0, stream>>>(cmean, temporal);
    kB_cons<<<BT / 256, 256, 0, stream>>>(ssq, dotv, spec, temporal, wts, cons, consq);
    kC_scan16<<<1, 256, 0, stream>>>(consq, CSq);
    kD_prepare<<<BT / 256, 256, 0, stream>>>(cons, CSq, init, stepv, candf, counts);
    k_final<<<BT / 256, 256, 0, stream>>>(init, stepv, candf, counts, (float*)d_out);
}

// Round 23
// 124.972 us; speedup vs baseline: 1.9275x; 1.9275x over previous
//
#include <hip/hip_runtime.h>
#include <cstdint>

#define BB 16
#define MM 128
#define TT 12000
constexpr int BT = BB * TT; // 192000

// Q4-interleaved scan layout: element (row b, pos t), t=4g+j lives at
// q[(g*16 + b)*4 + j]  (one float4 per (group, row); 16 rows contiguous
// per group -> a 16-lane quad access covers 256 contiguous bytes).

// K1: per-column stats over the M axis, sequential in m (reference order).
// anti-fma via `#pragma clang fp contract(off)` (proven round 13).
__global__ void k1_colstats(const float* __restrict__ mel,
                            float* __restrict__ ssq,
                            float* __restrict__ dotv,
                            float* __restrict__ cmean,
                            unsigned int* __restrict__ counts) {
    if (blockIdx.x == 0 && blockIdx.y == 0 && threadIdx.x < 8)
        counts[threadIdx.x] = 0u;
    const int b = blockIdx.y;
    const int t = blockIdx.x * blockDim.x + threadIdx.x;
    if (t >= TT) return;
    const float* base = mel + (size_t)b * MM * TT;
    float accd = 0.f, accq = 0.f, accs = 0.f;
    {
#pragma clang fp contract(off)
        for (int m = 0; m < MM; ++m) {
            const float* rowp = base + (size_t)m * TT;
            float cur = rowp[t];
            float prev = (t > 0) ? rowp[t - 1] : 0.f;
            accd += prev * cur;
            accq += cur * cur;
            accs += cur;
        }
    }
    size_t i = (size_t)b * TT + t;
    ssq[i] = accq; dotv[i] = accd; cmean[i] = accs * (1.0f / MM);
}

// kA: temporal = 1 - std(smooth, ddof=1). Row staged to LDS once.
__global__ void kA_temporal(const float* __restrict__ cmean,
                            float* __restrict__ temporal) {
    const int b = blockIdx.x;
    const int tid = threadIdx.x;
    __shared__ __align__(16) float row_s[TT];
    __shared__ float red[256];
    __shared__ float mean_s;
    const float4* c4 = (const float4*)(cmean + (size_t)b * TT);
    float4* r4 = (float4*)row_s;
    for (int i = tid; i < TT / 4; i += 256) r4[i] = c4[i];
    __syncthreads();

    float s = 0.f;
    for (int t = tid; t < TT; t += 256) {
        float v = 0.f;
        int lo = t - 2 < 0 ? 0 : t - 2;
        int hi = t + 2 >= TT ? TT - 1 : t + 2;
        for (int j = lo; j <= hi; ++j) v += row_s[j];
        s += v / 5.0f;
    }
    red[tid] = s; __syncthreads();
    for (int o = 128; o > 0; o >>= 1) {
        if (tid < o) red[tid] += red[tid + o];
        __syncthreads();
    }
    if (tid == 0) mean_s = red[0] / (float)TT;
    __syncthreads();
    float mean = mean_s;
    float ss = 0.f;
    for (int t = tid; t < TT; t += 256) {
        float v = 0.f;
        int lo = t - 2 < 0 ? 0 : t - 2;
        int hi = t + 2 >= TT ? TT - 1 : t + 2;
        for (int j = lo; j <= hi; ++j) v += row_s[j];
        float sm = v / 5.0f - mean;
        ss += sm * sm;
    }
    red[tid] = ss; __syncthreads();
    for (int o = 128; o > 0; o >>= 1) {
        if (tid < o) red[tid] += red[tid + o];
        __syncthreads();
    }
    if (tid == 0) {
        float var = red[0] / (float)(TT - 1);
        temporal[b] = 1.0f - sqrtf(var);
    }
}

// kB: cons — same arithmetic as the passing version; additionally writes
// the Q4-interleaved copy for the scan (same value, extra store only).
__global__ void kB_cons(const float* __restrict__ ssq,
                        const float* __restrict__ dotv,
                        const float* __restrict__ spec,
                        const float* __restrict__ temporal,
                        const float* __restrict__ wraw,
                        float* __restrict__ cons,
                        float* __restrict__ consq) {
    const int idx = blockIdx.x * 256 + threadIdx.x;
    const int b = idx / TT;
    const int t = idx - b * TT;
    float x0 = wraw[0], x1 = wraw[1], x2 = wraw[2];
    float mx = fmaxf(x0, fmaxf(x1, x2));
    float e0 = expf(x0 - mx), e1 = expf(x1 - mx), e2 = expf(x2 - mx);
    float es = (e0 + e1) + e2;
    float w0 = e0 / es, w1 = e1 / es, w2 = e2 / es;
    float mel_sim, spec_sim;
    if (t == 0) { mel_sim = 0.f; spec_sim = 1.f; }
    else {
        float na = fmaxf(sqrtf(ssq[idx - 1]), 1e-8f);
        float nb = fmaxf(sqrtf(ssq[idx]),     1e-8f);
        float den = na * nb; asm volatile("" : "+v"(den));
        mel_sim = dotv[idx] / den;
        float d = fabsf(spec[idx] - spec[idx - 1]);
        spec_sim = 1.0f / (1.0f + d);
    }
    float pa = w0 * mel_sim;     asm volatile("" : "+v"(pa));
    float pb = w1 * spec_sim;    asm volatile("" : "+v"(pb));
    float pc = w2 * temporal[b]; asm volatile("" : "+v"(pc));
    float c = (pa + pb) + pc;
    cons[idx] = c;
    consq[((t >> 2) * 16 + b) * 4 + (t & 3)] = c;
}

// ROUND-18 PROVEN SCAN (68 us): one group = 4 dependent adds (bitwise the
// reference cumsum chain), carry snapshot BEFORE the prefetch load
// (round-5 WAR discipline), Q4 store (256 contiguous bytes), prefetch
// load 24 groups ahead; ONE vmcnt(40) wait per 4-group sub-batch.
#define SCQ(Q0a,Q0b,Q0c,Q0d, Q1a,Q1b,Q1c,Q1d, Q2a,Q2b,Q2c,Q2d, Q3a,Q3b,Q3c,Q3d) \
    "s_waitcnt vmcnt(40)\n\t" \
    "v_add_f32 v" Q0a ", v43, v" Q0a "\n\t" \
    "v_add_f32 v" Q0b ", v" Q0a ", v" Q0b "\n\t" \
    "v_add_f32 v" Q0c ", v" Q0b ", v" Q0c "\n\t" \
    "v_add_f32 v" Q0d ", v" Q0c ", v" Q0d "\n\t" \
    "v_add_f32 v" Q1a ", v" Q0d ", v" Q1a "\n\t" \
    "v_add_f32 v" Q1b ", v" Q1a ", v" Q1b "\n\t" \
    "v_add_f32 v" Q1c ", v" Q1b ", v" Q1c "\n\t" \
    "v_add_f32 v" Q1d ", v" Q1c ", v" Q1d "\n\t" \
    "v_add_f32 v" Q2a ", v" Q1d ", v" Q2a "\n\t" \
    "v_add_f32 v" Q2b ", v" Q2a ", v" Q2b "\n\t" \
    "v_add_f32 v" Q2c ", v" Q2b ", v" Q2c "\n\t" \
    "v_add_f32 v" Q2d ", v" Q2c ", v" Q2d "\n\t" \
    "v_add_f32 v" Q3a ", v" Q2d ", v" Q3a "\n\t" \
    "v_add_f32 v" Q3b ", v" Q3a ", v" Q3b "\n\t" \
    "v_add_f32 v" Q3c ", v" Q3b ", v" Q3c "\n\t" \
    "v_add_f32 v" Q3d ", v" Q3c ", v" Q3d "\n\t" \
    "v_mov_b32 v43, v" Q3d "\n\t" \
    "global_store_dwordx4 v40, v[" Q0a ":" Q0d "], %1 offset:0\n\t" \
    "global_store_dwordx4 v40, v[" Q1a ":" Q1d "], %1 offset:256\n\t" \
    "global_store_dwordx4 v40, v[" Q2a ":" Q2d "], %1 offset:512\n\t" \
    "global_store_dwordx4 v40, v[" Q3a ":" Q3d "], %1 offset:768\n\t" \
    "global_load_dwordx4 v[" Q0a ":" Q0d "], v42, %0 offset:0\n\t" \
    "global_load_dwordx4 v[" Q1a ":" Q1d "], v42, %0 offset:256\n\t" \
    "global_load_dwordx4 v[" Q2a ":" Q2d "], v42, %0 offset:512\n\t" \
    "global_load_dwordx4 v[" Q3a ":" Q3d "], v42, %0 offset:768\n\t" \
    "v_add_u32 v40, 0x400, v40\n\t" \
    "v_add_u32 v42, 0x400, v42\n\t"

// kC: 16-lane SIMT scan in asm on the Q4-interleaved layout (round-18
// verbatim) — every quad access is 256 contiguous bytes; 24-group ring.
__global__ void __launch_bounds__(64)
kC_scan16(const float* __restrict__ consq,
          float* __restrict__ CSq) {
    const int r = threadIdx.x;
    if (r >= BB) return;
    uint32_t voff = (uint32_t)(r * 16);   // per-lane byte offset in a group
    asm volatile(
        "v_mov_b32 v40, %2\n\t"
        "v_mov_b32 v43, 0\n\t"
        // prologue: fill 24-quad ring (groups 0..23)
        "global_load_dwordx4 v[48:51],   v40, %0 offset:0\n\t"
        "global_load_dwordx4 v[52:55],   v40, %0 offset:256\n\t"
        "global_load_dwordx4 v[56:59],   v40, %0 offset:512\n\t"
        "global_load_dwordx4 v[60:63],   v40, %0 offset:768\n\t"
        "global_load_dwordx4 v[64:67],   v40, %0 offset:1024\n\t"
        "global_load_dwordx4 v[68:71],   v40, %0 offset:1280\n\t"
        "global_load_dwordx4 v[72:75],   v40, %0 offset:1536\n\t"
        "global_load_dwordx4 v[76:79],   v40, %0 offset:1792\n\t"
        "global_load_dwordx4 v[80:83],   v40, %0 offset:2048\n\t"
        "global_load_dwordx4 v[84:87],   v40, %0 offset:2304\n\t"
        "global_load_dwordx4 v[88:91],   v40, %0 offset:2560\n\t"
        "global_load_dwordx4 v[92:95],   v40, %0 offset:2816\n\t"
        "global_load_dwordx4 v[96:99],   v40, %0 offset:3072\n\t"
        "global_load_dwordx4 v[100:103], v40, %0 offset:3328\n\t"
        "global_load_dwordx4 v[104:107], v40, %0 offset:3584\n\t"
        "global_load_dwordx4 v[108:111], v40, %0 offset:3840\n\t"
        "v_add_u32 v41, 0x1000, v40\n\t"
        "global_load_dwordx4 v[112:115], v41, %0 offset:0\n\t"
        "global_load_dwordx4 v[116:119], v41, %0 offset:256\n\t"
        "global_load_dwordx4 v[120:123], v41, %0 offset:512\n\t"
        "global_load_dwordx4 v[124:127], v41, %0 offset:768\n\t"
        "global_load_dwordx4 v[128:131], v41, %0 offset:1024\n\t"
        "global_load_dwordx4 v[132:135], v41, %0 offset:1280\n\t"
        "global_load_dwordx4 v[136:139], v41, %0 offset:1536\n\t"
        "global_load_dwordx4 v[140:143], v41, %0 offset:1792\n\t"
        "v_add_u32 v42, 0x1800, v40\n\t"   // load base: 24 groups ahead
        "s_waitcnt vmcnt(0)\n\t"
        "s_mov_b32 s20, 125\n\t"           // 125 passes x 6 SBs x 4 groups = 3000
        "3:\n\t"
        SCQ("48","49","50","51",  "52","53","54","55",
            "56","57","58","59",  "60","61","62","63")
        SCQ("64","65","66","67",  "68","69","70","71",
            "72","73","74","75",  "76","77","78","79")
        SCQ("80","81","82","83",  "84","85","86","87",
            "88","89","90","91",  "92","93","94","95")
        SCQ("96","97","98","99",  "100","101","102","103",
            "104","105","106","107", "108","109","110","111")
        SCQ("112","113","114","115", "116","117","118","119",
            "120","121","122","123", "124","125","126","127")
        SCQ("128","129","130","131", "132","133","134","135",
            "136","137","138","139", "140","141","142","143")
        "s_sub_u32 s20, s20, 1\n\t"
        "s_cmp_lg_u32 s20, 0\n\t"
        "s_cbranch_scc1 3b\n\t"
        "s_waitcnt vmcnt(0)\n\t"
        :
        : "s"(consq), "s"(CSq), "v"(voff)
        : "v40", "v41", "v42", "v43",
          "v48", "v49", "v50", "v51", "v52", "v53", "v54", "v55",
          "v56", "v57", "v58", "v59", "v60", "v61", "v62", "v63",
          "v64", "v65", "v66", "v67", "v68", "v69", "v70", "v71",
          "v72", "v73", "v74", "v75", "v76", "v77", "v78", "v79",
          "v80", "v81", "v82", "v83", "v84", "v85", "v86", "v87",
          "v88", "v89", "v90", "v91", "v92", "v93", "v94", "v95",
          "v96", "v97", "v98", "v99", "v100", "v101", "v102", "v103",
          "v104", "v105", "v106", "v107", "v108", "v109", "v110", "v111",
          "v112", "v113", "v114", "v115", "v116", "v117", "v118", "v119",
          "v120", "v121", "v122", "v123", "v124", "v125", "v126", "v127",
          "v128", "v129", "v130", "v131", "v132", "v133", "v134", "v135",
          "v136", "v137", "v138", "v139", "v140", "v141", "v142", "v143",
          "s20", "scc", "memory");
}

// kD: flags ONLY — per-iteration "any nonzero adjustment" on the
// never-done trajectory (same expressions as before, no stepv/candf
// stores). k_final recomputes step/cand itself (bitwise identical).
__global__ void kD_flags(const float* __restrict__ cons,
                         const float* __restrict__ CSq,
                         const float* __restrict__ init,
                         unsigned int* __restrict__ counts) {
    const int idx = blockIdx.x * 256 + threadIdx.x;
    const int b = idx / TT;
    const int t = idx - b * TT;
    __shared__ unsigned sflag[5];
    if (threadIdx.x < 5) sflag[threadIdx.x] = 0u;
    __syncthreads();

    int lo = t - 2; if (lo < 0) lo = 0;
    int hi = t + 3; if (hi > TT) hi = TT;
    int uh = hi - 1;
    float csH = CSq[((uh >> 2) * 16 + b) * 4 + (uh & 3)];
    float csL = 0.f;
    if (lo > 0) {
        int ul = lo - 1;
        csL = CSq[((ul >> 2) * 16 + b) * 4 + (ul & 3)];
    }
    float local = (csH - csL) / (float)(hi - lo);
    float dir = (local > 0.7f) ? -0.1f : ((local < 0.4f) ? 0.1f : 0.0f);
    bool interior = (t >= 1) && (t <= TT - 2);
    float step = interior ? dir : 0.0f;
    float g = (t == 0) ? 0.f : fabsf(cons[idx] - cons[idx - 1]);
    float cand = (g > 0.15f) ? 1.f : 0.f;
    float r = init[idx];
    bool nz[5];
#pragma unroll
    for (int j = 0; j < 5; ++j) {
        float adj = (fmaxf(cand, r) > 0.5f) ? step : 0.0f;
        nz[j] = (adj != 0.0f);
        r = fminf(fmaxf(r + adj, 0.0f), 1.0f);
    }
    const int lane = threadIdx.x & 63;
#pragma unroll
    for (int j = 0; j < 5; ++j) {
        unsigned long long mb = __ballot(nz[j]);
        if (lane == 0 && mb) atomicOr(&sflag[j], 1u);   // LDS-scope, cheap
    }
    __syncthreads();
    if (threadIdx.x < 5 && sflag[threadIdx.x]) counts[threadIdx.x] = 1u;
}

// K_final: recompute step/cand (bitwise same as kD) and replay the 5-iter
// trajectory, freezing at the first iteration whose flag is 0.
__global__ void k_final(const float* __restrict__ cons,
                        const float* __restrict__ CSq,
                        const float* __restrict__ init,
                        const unsigned int* __restrict__ counts,
                        float* __restrict__ outp) {
    const int idx = blockIdx.x * 256 + threadIdx.x;
    const int b = idx / TT;
    const int t = idx - b * TT;

    int lo = t - 2; if (lo < 0) lo = 0;
    int hi = t + 3; if (hi > TT) hi = TT;
    int uh = hi - 1;
    float csH = CSq[((uh >> 2) * 16 + b) * 4 + (uh & 3)];
    float csL = 0.f;
    if (lo > 0) {
        int ul = lo - 1;
        csL = CSq[((ul >> 2) * 16 + b) * 4 + (ul & 3)];
    }
    float local = (csH - csL) / (float)(hi - lo);
    float dir = (local > 0.7f) ? -0.1f : ((local < 0.4f) ? 0.1f : 0.0f);
    bool interior = (t >= 1) && (t <= TT - 2);
    float step = interior ? dir : 0.0f;
    float g = (t == 0) ? 0.f : fabsf(cons[idx] - cons[idx - 1]);
    float cand = (g > 0.15f) ? 1.f : 0.f;

    float r = init[idx];
    unsigned c[5];
#pragma unroll
    for (int j = 0; j < 5; ++j) c[j] = counts[j];
#pragma unroll
    for (int j = 0; j < 5; ++j) {
        if (c[j] == 0u) break;
        float adj = (fmaxf(cand, r) > 0.5f) ? step : 0.0f;
        r = fminf(fmaxf(r + adj, 0.0f), 1.0f);
    }
    outp[idx] = r;
}

extern "C" void kernel_launch(void* const* d_in, const int* in_sizes, int n_in,
                              void* d_out, int out_size, void* d_ws, size_t ws_size,
                              hipStream_t stream) {
    const float* mel  = (const float*)d_in[0];
    const float* spec = (const float*)d_in[1];
    const float* init = (const float*)d_in[2];
    const float* wts  = (const float*)d_in[3];

    float* ws = (float*)d_ws;
    float* ssq   = ws;                 // 192000
    float* dotv  = ws + 192000;        // 192000
    float* cmean = ws + 384000;        // 192000
    float* cons  = ws + 576000;        // 192000 (row-major, for grads)
    float* consq = ws + 768000;        // 192000 (Q4-interleaved)
    float* CSq   = ws + 960000;        // 198144 (Q4; absorbs 24-group tail prefetch)
    float* temporal = ws + 1158144;    // 16
    unsigned int* counts = (unsigned int*)(ws + 1158160); // 8 u32

    dim3 g1((TT + 255) / 256, BB);
    k1_colstats<<<g1, 256, 0, stream>>>(mel, ssq, dotv, cmean, counts);
    kA_temporal<<<BB, 256, 0, stream>>>(cmean, temporal);
    kB_cons<<<BT / 256, 256, 0, stream>>>(ssq, dotv, spec, temporal, wts, cons, consq);
    kC_scan16<<<1, 64, 0, stream>>>(consq, CSq);
    kD_flags<<<BT / 256, 256, 0, stream>>>(cons, CSq, init, counts);
    k_final<<<BT / 256, 256, 0, stream>>>(cons, CSq, init, counts, (float*)d_out);
}